// Round 13
// baseline (35.671 us; speedup 1.0000x reference)
//
#include <hip/hip_runtime.h>
#include <hip/hip_bf16.h>
#include <math.h>

// Problem constants
#define NN 128
#define LL 1024

typedef __attribute__((ext_vector_type(8))) short short8;
typedef __attribute__((ext_vector_type(4))) float f32x4;

__device__ __forceinline__ float sigm(float x) {
    return __builtin_amdgcn_rcpf(1.f + __expf(-x));
}

__device__ __forceinline__ short bf16s(float x) {
    __hip_bfloat16 h = __float2bfloat16(x);   // RNE; compiler pairs into v_cvt_pk_bf16_f32
    union { __hip_bfloat16 hh; short s; } u; u.hh = h;
    return u.s;
}

__device__ __forceinline__ short8 pack_bf8(float4 a, float4 b) {
    short8 r;
    r[0] = bf16s(a.x); r[1] = bf16s(a.y); r[2] = bf16s(a.z); r[3] = bf16s(a.w);
    r[4] = bf16s(b.x); r[5] = bf16s(b.y); r[6] = bf16s(b.z); r[7] = bf16s(b.w);
    return r;
}

// ---------------------------------------------------------------------------
// Node A: 512 independent blocks (n = b>>2, quarter c = b&3; 256 rows each).
//   production: per-block redundant Wt/cv for its n (all in LDS)
//   main: 2 sub-chunks x 128 rows: stage bf16 -> MFMA scores -> MLP -> att
//         -> T accum (regs, fp32 global re-read, L2-hot)
//   epilogue: U = T*Wv^T; contrib[64] = U*Wu^T -> ws (plain store)
// ---------------------------------------------------------------------------
__global__ void __launch_bounds__(256, 2) fused_kernel(
    const float* __restrict__ seq, const float* __restrict__ target,
    const float* __restrict__ memv, const float* __restrict__ Wk,
    const float* __restrict__ Wq, const float* __restrict__ Wv,
    const float* __restrict__ Wu, const float* __restrict__ W1,
    const float* __restrict__ b1, const float* __restrict__ W2,
    const float* __restrict__ b2,
    float* __restrict__ att_out, float* __restrict__ contrib)
{
    const int b = blockIdx.x;
    const int n = b >> 2;
    const int c = b & 3;
    const int t = threadIdx.x;
    const int lane = t & 63;
    const int w = t >> 6;          // wave 0..3

    __shared__ __align__(16) float tl[64];
    __shared__ __align__(16) float ml[64];
    __shared__ float vh[64];
    __shared__ float wh[512];                         // [d][j]
    __shared__ float cp[64];
    __shared__ float cvl[32];
    __shared__ __align__(16) short wt_lds[32 * 72];   // [hj][k] bf16
    __shared__ __align__(16) short seq_bf[128 * 72];  // [l][k] bf16
    __shared__ __align__(16) float att_l[512];        // [l][h]
    __shared__ __align__(16) float Tp_l[4][256];
    __shared__ float T_l[256];                        // [p = h*64+k]
    __shared__ __align__(16) float U_l[256];
    __shared__ float op[256];
    // ~35.5 KB

    // ======================= production (all 4 heads) =====================
    if (t < 64)       tl[t] = target[n * 64 + t];
    else if (t < 128) ml[t - 64] = memv[n * 64 + (t - 64)];
    __syncthreads();

    for (int h = 0; h < 4; ++h) {
        // v[d] = sum_k Wq[h*64+d, k] * target[k]
        {
            const int d = t >> 2, kq = t & 3;
            const float4* wq4 = reinterpret_cast<const float4*>(Wq + (h * 64 + d) * 64 + kq * 16);
            const float4* tl4 = reinterpret_cast<const float4*>(tl + kq * 16);
            float s = 0.f;
            #pragma unroll
            for (int cc = 0; cc < 4; ++cc) {
                const float4 a = wq4[cc], bb = tl4[cc];
                s = fmaf(a.x, bb.x, s); s = fmaf(a.y, bb.y, s);
                s = fmaf(a.z, bb.z, s); s = fmaf(a.w, bb.w, s);
            }
            s += __shfl_xor(s, 1);
            s += __shfl_xor(s, 2);
            if (kq == 0) vh[d] = s;
        }
        __syncthreads();

        // w[d][j]; c partials
        {
            const int d = t & 63, jh = t >> 6;
            const float vv = vh[d], mm = ml[d];
            #pragma unroll
            for (int r = 0; r < 2; ++r) {
                const int j = jh + r * 4;
                float wv = -W1[j * 256 + d] - W1[j * 256 + 128 + d];
                wv = fmaf(W1[j * 256 + 64 + d], vv, wv);
                wv = fmaf(W1[j * 256 + 192 + d], mm, wv);
                wh[d * 8 + j] = wv;
            }
        }
        if (t < 64) {
            const int j = t >> 3, sl = t & 7;
            float s = 0.f;
            #pragma unroll
            for (int d8 = 0; d8 < 8; ++d8) {
                const int d = sl * 8 + d8;
                s = fmaf(W1[j * 256 + d], vh[d], s);
                s = fmaf(W1[j * 256 + 128 + d], ml[d], s);
            }
            cp[t] = s;
        }
        __syncthreads();

        if (t < 8) {
            float s = b1[t];
            #pragma unroll
            for (int sl = 0; sl < 8; ++sl) s += cp[t * 8 + sl];
            cvl[h * 8 + t] = s;
        }
        // Wt[hj][k] = sum_d Wk[h*64+d, k] * w[d][j]; k on lanes (coalesced)
        {
            const int k = t & 63, jp = t >> 6;
            float s0 = 0.f, s1 = 0.f;
            #pragma unroll 8
            for (int d = 0; d < 64; ++d) {
                const float wk = Wk[(h * 64 + d) * 64 + k];
                s0 = fmaf(wk, wh[d * 8 + jp], s0);
                s1 = fmaf(wk, wh[d * 8 + jp + 4], s1);
            }
            wt_lds[(h * 8 + jp) * 72 + k]     = bf16s(s0);
            wt_lds[(h * 8 + jp + 4) * 72 + k] = bf16s(s1);
        }
        __syncthreads();
    }

    // ======================= main: 2 sub-chunks of 128 rows ===============
    const float* sbase = seq + ((size_t)n * LL + c * 256) * 64;

    const int rt = w & 1;            // hj 16-block
    const int ctb = w >> 1;          // coltile base (0..1); tiles ctb + 2*cc
    const int g = lane >> 4;         // k-group / C-row group
    const int cidx = lane & 15;      // col within tile

    short8 afrag[2];
    #pragma unroll
    for (int ks = 0; ks < 2; ++ks)
        afrag[ks] = *reinterpret_cast<const short8*>(
            wt_lds + (rt * 16 + cidx) * 72 + ks * 32 + g * 8);

    const float4 w2v = *reinterpret_cast<const float4*>(W2 + 4 * (g & 1));
    const float b2v = b2[0];
    const float cv0 = cvl[rt * 16 + g * 4 + 0];
    const float cv1 = cvl[rt * 16 + g * 4 + 1];
    const float cv2 = cvl[rt * 16 + g * 4 + 2];
    const float cv3 = cvl[rt * 16 + g * 4 + 3];

    float th0 = 0.f, th1 = 0.f, th2 = 0.f, th3 = 0.f;

    // stage sc0 into LDS; prefetch sc1 into regs (hidden under sc0 compute)
    {
        #pragma unroll
        for (int gg = 0; gg < 4; ++gg) {
            const int p8 = gg * 256 + t;
            const int l = p8 >> 3, seg = p8 & 7;
            const float* rp = sbase + l * 64 + seg * 8;
            const float4 a = *reinterpret_cast<const float4*>(rp);
            const float4 bb = *reinterpret_cast<const float4*>(rp + 4);
            *reinterpret_cast<short8*>(seq_bf + l * 72 + seg * 8) = pack_bf8(a, bb);
        }
    }
    float4 sw[8];
    {
        const float* scb1 = sbase + 128 * 64;
        #pragma unroll
        for (int gg = 0; gg < 4; ++gg) {
            const int p8 = gg * 256 + t;
            const int l = p8 >> 3, seg = p8 & 7;
            const float* rp = scb1 + l * 64 + seg * 8;
            sw[2 * gg]     = *reinterpret_cast<const float4*>(rp);
            sw[2 * gg + 1] = *reinterpret_cast<const float4*>(rp + 4);
        }
    }
    __syncthreads();

    #pragma unroll
    for (int sc = 0; sc < 2; ++sc) {
        const float* scb = sbase + sc * 128 * 64;

        // ---- score MFMAs + MLP: 4 coltiles per wave ----
        #pragma unroll
        for (int cc = 0; cc < 4; ++cc) {
            const int ct = ctb + cc * 2;
            const int l = ct * 16 + cidx;
            f32x4 acc;
            acc[0] = cv0; acc[1] = cv1; acc[2] = cv2; acc[3] = cv3;
            const short8 bf0 = *reinterpret_cast<const short8*>(seq_bf + l * 72 + g * 8);
            const short8 bf1 = *reinterpret_cast<const short8*>(seq_bf + l * 72 + 32 + g * 8);
            acc = __builtin_amdgcn_mfma_f32_16x16x32_bf16(afrag[0], bf0, acc, 0, 0, 0);
            acc = __builtin_amdgcn_mfma_f32_16x16x32_bf16(afrag[1], bf1, acc, 0, 0, 0);

            float local = w2v.x * sigm(acc[0]);
            local = fmaf(w2v.y, sigm(acc[1]), local);
            local = fmaf(w2v.z, sigm(acc[2]), local);
            local = fmaf(w2v.w, sigm(acc[3]), local);
            local += __shfl_xor(local, 16);
            const float attv = sigm(b2v + local);
            if ((lane & 16) == 0) {
                const int hh = 2 * rt + (g >> 1);
                att_l[l * 4 + hh] = attv;
            }
        }
        __syncthreads();

        // ---- att store: 512 contiguous floats ----
        {
            float* dst = att_out + ((size_t)n * LL + c * 256 + sc * 128) * 4;
            dst[t] = att_l[t];
            dst[256 + t] = att_l[256 + t];
        }

        // ---- T accum: wave w covers rows [32w, 32w+32); lane = k ----
        {
            const float* sq = scb + (w * 32) * 64 + lane;
            #pragma unroll 4
            for (int li = 0; li < 32; ++li) {
                const float s = sq[li * 64];              // coalesced, L2-hot
                const float4 a = *reinterpret_cast<const float4*>(att_l + (w * 32 + li) * 4);
                th0 = fmaf(a.x, s, th0); th1 = fmaf(a.y, s, th1);
                th2 = fmaf(a.z, s, th2); th3 = fmaf(a.w, s, th3);
            }
        }

        if (sc == 0) {
            // overwrite seq_bf with sc1 (all score reads done at post-MLP barrier)
            #pragma unroll
            for (int gg = 0; gg < 4; ++gg) {
                const int p8 = gg * 256 + t;
                const int l = p8 >> 3, seg = p8 & 7;
                *reinterpret_cast<short8*>(seq_bf + l * 72 + seg * 8) =
                    pack_bf8(sw[2 * gg], sw[2 * gg + 1]);
            }
            __syncthreads();   // seq_bf(sc1) visible; att_l safe to overwrite
        }
    }

    Tp_l[w][0 * 64 + lane] = th0;
    Tp_l[w][1 * 64 + lane] = th1;
    Tp_l[w][2 * 64 + lane] = th2;
    Tp_l[w][3 * 64 + lane] = th3;
    __syncthreads();

    // ======================= epilogue =====================================
    T_l[t] = Tp_l[0][t] + Tp_l[1][t] + Tp_l[2][t] + Tp_l[3][t];
    __syncthreads();

    // U[hd] = sum_k T[h][k] * Wv[hd][k]; (hd4, kq) threads, 4 rows each
    {
        const int hd4 = t >> 2, kq = t & 3;
        #pragma unroll
        for (int r = 0; r < 4; ++r) {
            const int hd = r * 64 + hd4;
            const float4* wv4 = reinterpret_cast<const float4*>(Wv + hd * 64 + kq * 16);
            const float4* t4  = reinterpret_cast<const float4*>(T_l + (hd >> 6) * 64 + kq * 16);
            float s = 0.f;
            #pragma unroll
            for (int i = 0; i < 4; ++i) {
                const float4 a = wv4[i], bb = t4[i];
                s = fmaf(a.x, bb.x, s); s = fmaf(a.y, bb.y, s);
                s = fmaf(a.z, bb.z, s); s = fmaf(a.w, bb.w, s);
            }
            s += __shfl_xor(s, 1);
            s += __shfl_xor(s, 2);
            if (kq == 0) U_l[hd] = s;
        }
    }
    __syncthreads();

    // contrib[q] = sum_hd U[hd] * Wu[q][hd]; 4-way hd split
    {
        const int q = t & 63, qr = t >> 6;
        const float4* wu4 = reinterpret_cast<const float4*>(Wu + q * 256 + qr * 64);
        const float4* u4  = reinterpret_cast<const float4*>(U_l + qr * 64);
        float s = 0.f;
        #pragma unroll
        for (int i = 0; i < 16; ++i) {
            const float4 a = wu4[i], bb = u4[i];
            s = fmaf(a.x, bb.x, s); s = fmaf(a.y, bb.y, s);
            s = fmaf(a.z, bb.z, s); s = fmaf(a.w, bb.w, s);
        }
        op[t] = s;
    }
    __syncthreads();
    if (t < 64)
        contrib[(n * 4 + c) * 64 + t] = op[t] + op[64 + t] + op[128 + t] + op[192 + t];
}

// ---------------------------------------------------------------------------
// Node B: out[n,q] = bu[q] + sum_c contrib[n][c][q]   (32 blocks, trivial)
// ---------------------------------------------------------------------------
__global__ void __launch_bounds__(256) reduce_kernel(
    const float* __restrict__ contrib, const float* __restrict__ bu,
    float* __restrict__ out)
{
    const int idx = blockIdx.x * 256 + threadIdx.x;   // 8192 = 128*64
    const int n = idx >> 6, q = idx & 63;
    out[idx] = bu[q] + contrib[(n * 4 + 0) * 64 + q] + contrib[(n * 4 + 1) * 64 + q]
             + contrib[(n * 4 + 2) * 64 + q] + contrib[(n * 4 + 3) * 64 + q];
}

extern "C" void kernel_launch(void* const* d_in, const int* in_sizes, int n_in,
                              void* d_out, int out_size, void* d_ws, size_t ws_size,
                              hipStream_t stream) {
    const float* seq    = (const float*)d_in[0];
    const float* target = (const float*)d_in[1];
    const float* memv   = (const float*)d_in[2];
    const float* Wk     = (const float*)d_in[3];
    const float* Wq     = (const float*)d_in[4];
    const float* Wv     = (const float*)d_in[5];
    const float* Wu     = (const float*)d_in[6];
    const float* bu     = (const float*)d_in[7];
    const float* W1     = (const float*)d_in[8];
    const float* b1     = (const float*)d_in[9];
    const float* W2     = (const float*)d_in[10];
    const float* b2     = (const float*)d_in[11];

    float* out = (float*)d_out;             // [128*64]
    float* att = out + NN * 64;             // [128*1024*4]

    float* contrib = (float*)d_ws;          // [128][4][64]

    fused_kernel<<<NN * 4, 256, 0, stream>>>(seq, target, memv, Wk, Wq, Wv, Wu,
                                             W1, b1, W2, b2, att, contrib);
    reduce_kernel<<<32, 256, 0, stream>>>(contrib, bu, out);
}

// Round 14
// 21.864 us; speedup vs baseline: 1.6315x; 1.6315x over previous
//
#include <hip/hip_runtime.h>
#include <hip/hip_bf16.h>
#include <math.h>

// Problem constants
#define NN 128
#define LL 1024
#define HH 4
#define DD 64
#define NCHUNK 8          // chunks per n (128 rows each)
#define CROWS 128

// workspace layout (floats)
//   Zt  : [256(p=h*64+k)][64 q]   @ 0       (16384)
//   cv  : [N][32(hj)]             @ 16384   (4096)
//   Wtb : [N][32(hj)][64 k] bf16  @ 20480
#define WS_ZT  0
#define WS_C   16384
#define WS_WTB 20480

typedef __attribute__((ext_vector_type(8))) short short8;
typedef __attribute__((ext_vector_type(4))) float f32x4;

__device__ __forceinline__ float sigm(float x) {
    return __builtin_amdgcn_rcpf(1.f + __expf(-x));
}

__device__ __forceinline__ short bf16s(float x) {
    __hip_bfloat16 h = __float2bfloat16(x);   // RNE; pairs into v_cvt_pk_bf16_f32
    union { __hip_bfloat16 hh; short s; } u; u.hh = h;
    return u.s;
}

__device__ __forceinline__ short8 pack_bf8(float4 a, float4 b) {
    short8 r;
    r[0] = bf16s(a.x); r[1] = bf16s(a.y); r[2] = bf16s(a.z); r[3] = bf16s(a.w);
    r[4] = bf16s(b.x); r[5] = bf16s(b.y); r[6] = bf16s(b.z); r[7] = bf16s(b.w);
    return r;
}

// ---------------------------------------------------------------------------
// K1: blocks 0..31   : out[n,q] = bu[q]          (init for K2's atomics)
//     blocks 32..95  : Zt[p,q]  = sum_d Wu[q,h*64+d]*Wv[h*64+d,k]  (p=h*64+k)
//     blocks 96..607 : per-(n,h) v, w, c, Wt(bf16) — Wk staged via LDS
// ---------------------------------------------------------------------------
__global__ void __launch_bounds__(256) precompute_kernel(
    const float* __restrict__ target, const float* __restrict__ memv,
    const float* __restrict__ Wk, const float* __restrict__ Wq,
    const float* __restrict__ Wv, const float* __restrict__ Wu,
    const float* __restrict__ W1, const float* __restrict__ b1,
    const float* __restrict__ bu,
    unsigned short* __restrict__ Wtb, float* __restrict__ cvg,
    float* __restrict__ Zt, float* __restrict__ out)
{
    const int b = blockIdx.x;
    const int t = threadIdx.x;

    if (b < 32) {
        const int idx = b * 256 + t;          // 8192 = 128*64
        out[idx] = bu[idx & 63];
        return;
    }
    if (b < 96) {
        // Zt: q = b-32; t = p = h*64+k. Wv read coalesced (k on lanes).
        const int q = b - 32;
        const int h = t >> 6, k = t & 63;
        float s = 0.f;
        #pragma unroll 8
        for (int d = 0; d < 64; ++d)
            s = fmaf(Wu[q * 256 + h * 64 + d], Wv[(h * 64 + d) * 64 + k], s);
        Zt[t * 64 + q] = s;
        return;
    }

    const int nh = b - 96;
    const int n = nh >> 2, h = nh & 3;

    __shared__ __align__(16) float tl[64];
    __shared__ __align__(16) float ml[64];
    __shared__ float vh[64];
    __shared__ float wh[64 * 8];              // [d][j]
    __shared__ float cp[64];
    __shared__ __align__(16) float wk_lds[64 * 64];   // Wk head tile, 16 KB

    if (t < 64)       tl[t] = target[n * 64 + t];
    else if (t < 128) ml[t - 64] = memv[n * 64 + (t - 64)];

    // ---- stage Wk head tile (coalesced; consumed after the pre-Wt sync) ----
    {
        const float4* src = reinterpret_cast<const float4*>(Wk + h * 4096);
        float4* dst = reinterpret_cast<float4*>(wk_lds);
        #pragma unroll
        for (int i = 0; i < 4; ++i)
            dst[i * 256 + t] = src[i * 256 + t];
    }
    __syncthreads();

    // ---- v[d] = sum_k Wq[h*64+d, k] * target[k]; (d, k-quarter) on threads ----
    {
        const int d = t >> 2, kq = t & 3;
        const float4* wq4 = reinterpret_cast<const float4*>(Wq + (h * 64 + d) * 64 + kq * 16);
        const float4* tl4 = reinterpret_cast<const float4*>(tl + kq * 16);
        float s = 0.f;
        #pragma unroll
        for (int c = 0; c < 4; ++c) {
            const float4 a = wq4[c], bb = tl4[c];
            s = fmaf(a.x, bb.x, s); s = fmaf(a.y, bb.y, s);
            s = fmaf(a.z, bb.z, s); s = fmaf(a.w, bb.w, s);
        }
        s += __shfl_xor(s, 1);
        s += __shfl_xor(s, 2);
        if (kq == 0) vh[d] = s;
    }
    __syncthreads();

    // ---- w[d][j] = -W1[j,d] - W1[j,128+d] + W1[j,64+d]*v[d] + W1[j,192+d]*m[d] ----
    {
        const int d = t & 63, jh = t >> 6;
        const float vv = vh[d], mm = ml[d];
        #pragma unroll
        for (int r = 0; r < 2; ++r) {
            const int j = jh + r * 4;
            float wv = -W1[j * 256 + d] - W1[j * 256 + 128 + d];
            wv = fmaf(W1[j * 256 + 64 + d], vv, wv);
            wv = fmaf(W1[j * 256 + 192 + d], mm, wv);
            wh[d * 8 + j] = wv;
        }
    }
    // ---- c[j] partials ----
    if (t < 64) {
        const int j = t >> 3, sl = t & 7;
        float s = 0.f;
        #pragma unroll
        for (int d8 = 0; d8 < 8; ++d8) {
            const int d = sl * 8 + d8;
            s = fmaf(W1[j * 256 + d], vh[d], s);
            s = fmaf(W1[j * 256 + 128 + d], ml[d], s);
        }
        cp[t] = s;
    }
    __syncthreads();
    if (t < 8) {
        float s = b1[t];
        #pragma unroll
        for (int sl = 0; sl < 8; ++sl) s += cp[t * 8 + sl];
        cvg[n * 32 + h * 8 + t] = s;
    }

    // ---- Wt[hj][k] = sum_d wk_lds[d][k] * w[d][j]; k on lanes, all-LDS ----
    {
        const int k = t & 63, jp = t >> 6;
        float s0 = 0.f, s1 = 0.f;
        #pragma unroll 8
        for (int d = 0; d < 64; ++d) {
            const float wk = wk_lds[d * 64 + k];
            s0 = fmaf(wk, wh[d * 8 + jp], s0);       // wh reads wave-uniform
            s1 = fmaf(wk, wh[d * 8 + jp + 4], s1);
        }
        unsigned short* dst = Wtb + ((size_t)n * 32 + h * 8) * 64;
        dst[jp * 64 + k]       = (unsigned short)bf16s(s0);
        dst[(jp + 4) * 64 + k] = (unsigned short)bf16s(s1);
    }
}

// ---------------------------------------------------------------------------
// K2: per (n, 128-row chunk):
//   stage seq chunk as bf16 in LDS (coalesced float4 -> cvt_pk -> b128)
//   score GEMM via MFMA (A = Wt bf16 LDS, B = seq bf16 LDS)
//   -> sigmoid MLP (j-reduce via shfl_xor 16) -> att_l[l][h]
//   -> T[h][k] = sum_l att*seq  (seq from LDS bf16 — no global re-read)
//   -> out[q] += sum_p T[p]*Zt[p][q]  (atomic)
// ---------------------------------------------------------------------------
__global__ void __launch_bounds__(256, 5) main_kernel(
    const float* __restrict__ seq, const unsigned short* __restrict__ Wtb,
    const float* __restrict__ cvg, const float* __restrict__ W2,
    const float* __restrict__ b2, const float* __restrict__ Zt,
    float* __restrict__ att_out, float* __restrict__ out)
{
    const int n = blockIdx.x >> 3;
    const int chunk = blockIdx.x & 7;
    const int l0 = chunk * CROWS;
    const int t = threadIdx.x;
    const int lane = t & 63;
    const int w = t >> 6;

    __shared__ __align__(16) short seq_bf[128 * 72];  // [l][k] bf16, 144B rows
    __shared__ __align__(16) short wt_lds[32 * 72];   // [hj][k] bf16
    __shared__ float cvl[32];
    __shared__ __align__(16) float att_l[512];        // [l][h]
    __shared__ __align__(16) float Tp_l[4][256];      // per-wave partial T
    __shared__ float T_l[256];                        // [p = h*64+k]
    __shared__ float op[256];
    // total ~30.7 KB -> 5 blocks/CU

    const float* sbase = seq + ((size_t)n * LL + l0) * 64;

    // ---- stage seq chunk as bf16: 4 x (two float4 = 32B contig per thread) ----
    #pragma unroll
    for (int g = 0; g < 4; ++g) {
        const int p4 = g * 256 + t;           // 8-float group id (1024 total)
        const int l = p4 >> 3, seg = p4 & 7;
        const float* rp = sbase + l * 64 + seg * 8;
        const float4 a = *reinterpret_cast<const float4*>(rp);
        const float4 bb = *reinterpret_cast<const float4*>(rp + 4);
        *reinterpret_cast<short8*>(seq_bf + l * 72 + seg * 8) = pack_bf8(a, bb);
    }
    // ---- stage Wt (bf16, 4KB) + cv ----
    {
        const int row = t >> 3, seg = t & 7;
        const int4 wv = *reinterpret_cast<const int4*>(
            Wtb + ((size_t)n * 32 + row) * 64 + seg * 8);
        *reinterpret_cast<int4*>(wt_lds + row * 72 + seg * 8) = wv;
    }
    if (t < 32) cvl[t] = cvg[n * 32 + t];
    __syncthreads();

    // ---- score MFMAs: wave w -> rowtile rt (hj 16-block), coltiles ctbase..+3 ----
    const int rt = w & 1;
    const int ctbase = (w >> 1) * 4;
    const int g = lane >> 4;          // k-group / C-row group
    const int cidx = lane & 15;       // col within tile

    short8 afrag[2];
    #pragma unroll
    for (int ks = 0; ks < 2; ++ks)
        afrag[ks] = *reinterpret_cast<const short8*>(
            wt_lds + (rt * 16 + cidx) * 72 + ks * 32 + g * 8);

    f32x4 acc[4];
    #pragma unroll
    for (int ct = 0; ct < 4; ++ct)
        #pragma unroll
        for (int r = 0; r < 4; ++r)
            acc[ct][r] = cvl[rt * 16 + g * 4 + r];

    #pragma unroll
    for (int ct = 0; ct < 4; ++ct) {
        const int l = (ctbase + ct) * 16 + cidx;
        const short8 bf0 = *reinterpret_cast<const short8*>(seq_bf + l * 72 + g * 8);
        const short8 bf1 = *reinterpret_cast<const short8*>(seq_bf + l * 72 + 32 + g * 8);
        acc[ct] = __builtin_amdgcn_mfma_f32_16x16x32_bf16(afrag[0], bf0, acc[ct], 0, 0, 0);
        acc[ct] = __builtin_amdgcn_mfma_f32_16x16x32_bf16(afrag[1], bf1, acc[ct], 0, 0, 0);
    }

    // ---- MLP: hmid = sigm(score); partial j-sum; partner group via shfl_xor 16 ----
    {
        const float4 w2v = *reinterpret_cast<const float4*>(W2 + 4 * (g & 1));
        const float b2v = b2[0];
        #pragma unroll
        for (int ct = 0; ct < 4; ++ct) {
            float local = w2v.x * sigm(acc[ct][0]);
            local = fmaf(w2v.y, sigm(acc[ct][1]), local);
            local = fmaf(w2v.z, sigm(acc[ct][2]), local);
            local = fmaf(w2v.w, sigm(acc[ct][3]), local);
            local += __shfl_xor(local, 16);
            const float attv = sigm(b2v + local);
            if ((lane & 16) == 0) {
                const int l = (ctbase + ct) * 16 + cidx;
                const int h = 2 * rt + (g >> 1);
                att_l[l * 4 + h] = attv;
            }
        }
    }
    __syncthreads();

    // ---- att store: 512 contiguous floats ([l][h] == reference layout) ----
    {
        float* dst = att_out + ((size_t)n * LL + l0) * 4;
        dst[t] = att_l[t];
        dst[256 + t] = att_l[256 + t];
    }

    // ---- T partials: wave w covers l in [32w, 32w+32); lane = k; seq from LDS ----
    {
        float th0 = 0.f, th1 = 0.f, th2 = 0.f, th3 = 0.f;
        #pragma unroll 4
        for (int li = 0; li < 32; ++li) {
            const int l = w * 32 + li;
            const float s = __uint_as_float(
                ((unsigned)(unsigned short)seq_bf[l * 72 + lane]) << 16);
            const float4 a = *reinterpret_cast<const float4*>(att_l + l * 4);
            th0 = fmaf(a.x, s, th0); th1 = fmaf(a.y, s, th1);
            th2 = fmaf(a.z, s, th2); th3 = fmaf(a.w, s, th3);
        }
        Tp_l[w][0 * 64 + lane] = th0;
        Tp_l[w][1 * 64 + lane] = th1;
        Tp_l[w][2 * 64 + lane] = th2;
        Tp_l[w][3 * 64 + lane] = th3;
    }
    __syncthreads();

    T_l[t] = Tp_l[0][t] + Tp_l[1][t] + Tp_l[2][t] + Tp_l[3][t];
    __syncthreads();

    // ---- out[q] += sum_p T[p] * Zt[p][q]; Zt lane-coalesced, T uniform ----
    {
        const int q = t & 63, wq = t >> 6;
        float s = 0.f;
        #pragma unroll 8
        for (int i = 0; i < 64; ++i) {
            const int p = wq * 64 + i;
            s = fmaf(T_l[p], Zt[p * 64 + q], s);
        }
        op[t] = s;
    }
    __syncthreads();
    if (t < 64) {
        const float s = op[t] + op[64 + t] + op[128 + t] + op[192 + t];
        atomicAdd(out + n * 64 + t, s);
    }
}

extern "C" void kernel_launch(void* const* d_in, const int* in_sizes, int n_in,
                              void* d_out, int out_size, void* d_ws, size_t ws_size,
                              hipStream_t stream) {
    const float* seq    = (const float*)d_in[0];
    const float* target = (const float*)d_in[1];
    const float* memv   = (const float*)d_in[2];
    const float* Wk     = (const float*)d_in[3];
    const float* Wq     = (const float*)d_in[4];
    const float* Wv     = (const float*)d_in[5];
    const float* Wu     = (const float*)d_in[6];
    const float* bu     = (const float*)d_in[7];
    const float* W1     = (const float*)d_in[8];
    const float* b1     = (const float*)d_in[9];
    const float* W2     = (const float*)d_in[10];
    const float* b2     = (const float*)d_in[11];

    float* out = (float*)d_out;             // [128*64]
    float* att = out + NN * DD;             // [128*1024*4]

    float* ws  = (float*)d_ws;
    float* Ztw = ws + WS_ZT;
    float* cvg = ws + WS_C;
    unsigned short* Wtb = (unsigned short*)(ws + WS_WTB);

    precompute_kernel<<<608, 256, 0, stream>>>(target, memv, Wk, Wq, Wv, Wu, W1, b1,
                                               bu, Wtb, cvg, Ztw, out);
    main_kernel<<<NN * NCHUNK, 256, 0, stream>>>(seq, Wtb, cvg, W2, b2, Ztw,
                                                 att, out);
}